// Round 1
// baseline (7754.189 us; speedup 1.0000x reference)
//
#include <hip/hip_runtime.h>

typedef unsigned short u16;
typedef unsigned int   u32;
typedef __attribute__((ext_vector_type(8)))  short  short8v;   // 8 x bf16 (as i16)
typedef __attribute__((ext_vector_type(4)))  float  f32x4;
typedef __attribute__((ext_vector_type(16))) float  f32x16;
typedef __attribute__((ext_vector_type(4)))  unsigned short ushort4v;

#define B_   32
#define T_   512
#define D_   1024
#define N4_  4096

// ---- workspace layout (bytes) ----
#define OFF_XN   0ull                 // xn bf16   [32*512*1024]      33554432
#define OFF_ZX   33554432ull          // Zx bf16   [512][32][4096]   134217728
#define OFF_KT   167772160ull         // kernel^T bf16 [4096][1024]    8388608
#define OFF_RT   176160768ull         // recurrent^T bf16 [4096][1024] 8388608
#define OFF_HB   184549376ull         // h double buffer bf16 2*[32][1024]
#define OFF_HL   184680448ull         // h_last fp32 [32][1024]
#define OFF_BAR  184811520ull         // barrier counter

__device__ inline u16 f2bf(float f) {
  union { float f; u32 u; } x; x.f = f;
  u32 r = x.u + 0x7FFFu + ((x.u >> 16) & 1u);   // RNE
  return (u16)(r >> 16);
}
__device__ inline float bf2f(u16 h) {
  union { u32 u; float f; } x; x.u = ((u32)h) << 16; return x.f;
}
__device__ inline float sigm(float x) { return 1.f / (1.f + __expf(-x)); }

// ---------------- init: zero h buffers + barrier ----------------
__global__ __launch_bounds__(256) void init_kernel(u32* hbuf, u32* bar) {
  int i = blockIdx.x * 256 + threadIdx.x;
  if (i < 32768) hbuf[i] = 0u;       // 2 * 32*1024 bf16 = 32768 dwords
  if (i < 32)    bar[i]  = 0u;
}

// ---------------- LN1: x fp32 -> xn bf16 ----------------
__global__ __launch_bounds__(256) void ln1_kernel(const float* __restrict__ x,
    const float* __restrict__ gam, const float* __restrict__ bet, u16* __restrict__ xn) {
  int row = blockIdx.x; int tid = threadIdx.x;
  const float* xr = x + (size_t)row * D_;
  float4 v = *(const float4*)(xr + tid * 4);
  float s  = v.x + v.y + v.z + v.w;
  float ss = v.x*v.x + v.y*v.y + v.z*v.z + v.w*v.w;
  #pragma unroll
  for (int o = 32; o > 0; o >>= 1) { s += __shfl_down(s, o); ss += __shfl_down(ss, o); }
  __shared__ float red[8];
  int w = tid >> 6, l = tid & 63;
  if (l == 0) { red[w] = s; red[4 + w] = ss; }
  __syncthreads();
  s  = red[0] + red[1] + red[2] + red[3];
  ss = red[4] + red[5] + red[6] + red[7];
  float mean = s * (1.f / D_);
  float var  = ss * (1.f / D_) - mean * mean;
  float rstd = rsqrtf(var + 1e-3f);
  float4 g = *(const float4*)(gam + tid * 4);
  float4 b = *(const float4*)(bet + tid * 4);
  ushort4v o4;
  o4.x = f2bf((v.x - mean) * rstd * g.x + b.x);
  o4.y = f2bf((v.y - mean) * rstd * g.y + b.y);
  o4.z = f2bf((v.z - mean) * rstd * g.z + b.z);
  o4.w = f2bf((v.w - mean) * rstd * g.w + b.w);
  *(ushort4v*)(xn + (size_t)row * D_ + tid * 4) = o4;
}

// ---------------- transpose [1024][4096] fp32 -> [4096][1024] bf16 ----------------
__global__ __launch_bounds__(256) void transpose_bf16(const float* __restrict__ W, u16* __restrict__ WT) {
  __shared__ float tile[32][33];
  int c0 = blockIdx.x * 32, r0 = blockIdx.y * 32;
  int tx = threadIdx.x, ty = threadIdx.y;
  #pragma unroll
  for (int i = ty; i < 32; i += 8)
    tile[i][tx] = W[(size_t)(r0 + i) * N4_ + c0 + tx];
  __syncthreads();
  #pragma unroll
  for (int i = ty; i < 32; i += 8)
    WT[(size_t)(c0 + i) * D_ + r0 + tx] = f2bf(tile[tx][i]);
}

// ---------------- GEMM: Zx = xn @ kernel + bias  (A[16384x1024] * Bt[4096x1024]^T) ----------------
// 128x128 tile, BK=32, 4 waves, reg-staged LDS, XOR-swizzled.
// Output remapped to [t][b][4096]: zrow = (row&511)*32 + (row>>9)
__global__ __launch_bounds__(256) void gemm_xk(const u16* __restrict__ A, const u16* __restrict__ Bt,
    const float* __restrict__ bias, u16* __restrict__ Zx) {
  __shared__ u16 As[128 * 32];
  __shared__ u16 Bs[128 * 32];
  int tid = threadIdx.x;
  int bm = blockIdx.x >> 5, bn = blockIdx.x & 31;
  int w = tid >> 6, l = tid & 63;
  int srow = tid >> 2, sk = (tid & 3) * 8;        // staging: row j*64+srow, k = sk..sk+8
  const u16* Ag = A  + (size_t)(bm * 128 + srow) * D_ + sk;
  const u16* Bg = Bt + (size_t)(bn * 128 + srow) * D_ + sk;
  int sb0 = (srow * 64 + sk * 2)          ^ ((srow & 3) << 4);
  int sb1 = ((srow + 64) * 64 + sk * 2)   ^ ((srow & 3) << 4);
  int wm = w >> 1, wn = w & 1;
  int frow = l & 15, fko = (l >> 4) * 16;         // fragment k byte offset
  f32x4 acc[4][4];
  #pragma unroll
  for (int mi = 0; mi < 4; ++mi)
    #pragma unroll
    for (int ni = 0; ni < 4; ++ni)
      #pragma unroll
      for (int j = 0; j < 4; ++j) acc[mi][ni][j] = 0.f;

  short8v ap0 = *(const short8v*)(Ag);
  short8v ap1 = *(const short8v*)(Ag + 64 * (size_t)D_);
  short8v bp0 = *(const short8v*)(Bg);
  short8v bp1 = *(const short8v*)(Bg + 64 * (size_t)D_);

  for (int kt = 0; kt < 32; ++kt) {
    __syncthreads();
    *(short8v*)((char*)As + sb0) = ap0;
    *(short8v*)((char*)As + sb1) = ap1;
    *(short8v*)((char*)Bs + sb0) = bp0;
    *(short8v*)((char*)Bs + sb1) = bp1;
    __syncthreads();
    if (kt < 31) {
      ap0 = *(const short8v*)(Ag + (kt + 1) * 32);
      ap1 = *(const short8v*)(Ag + 64 * (size_t)D_ + (kt + 1) * 32);
      bp0 = *(const short8v*)(Bg + (kt + 1) * 32);
      bp1 = *(const short8v*)(Bg + 64 * (size_t)D_ + (kt + 1) * 32);
    }
    short8v af[4], bfr[4];
    #pragma unroll
    for (int mi = 0; mi < 4; ++mi) {
      int r = wm * 64 + mi * 16 + frow;
      af[mi] = *(const short8v*)((char*)As + ((r * 64 + fko) ^ ((r & 3) << 4)));
    }
    #pragma unroll
    for (int ni = 0; ni < 4; ++ni) {
      int r = wn * 64 + ni * 16 + frow;
      bfr[ni] = *(const short8v*)((char*)Bs + ((r * 64 + fko) ^ ((r & 3) << 4)));
    }
    #pragma unroll
    for (int mi = 0; mi < 4; ++mi)
      #pragma unroll
      for (int ni = 0; ni < 4; ++ni)
        acc[mi][ni] = __builtin_amdgcn_mfma_f32_16x16x32_bf16(af[mi], bfr[ni], acc[mi][ni], 0, 0, 0);
  }
  // epilogue: +bias, bf16, remap rows to [t][b]
  #pragma unroll
  for (int mi = 0; mi < 4; ++mi) {
    #pragma unroll
    for (int ni = 0; ni < 4; ++ni) {
      int col = bn * 128 + wn * 64 + ni * 16 + (l & 15);
      float bv = bias[col];
      #pragma unroll
      for (int j = 0; j < 4; ++j) {
        int row = bm * 128 + wm * 64 + mi * 16 + (l >> 4) * 4 + j;
        int zrow = (row & 511) * 32 + (row >> 9);
        Zx[(size_t)zrow * N4_ + col] = f2bf(acc[mi][ni][j] + bv);
      }
    }
  }
}

// ---------------- persistent LSTM scan ----------------
// 32 WGs x 512 thr. WG wg owns units [wg*32, wg*32+32). 8 waves = 2 col-halves x 4 K-splits.
// R-slice preloaded in registers; h staged in swizzled LDS; c kept in LDS; 1 device barrier/step.
__global__ __launch_bounds__(512, 2) void lstm_scan(const u16* __restrict__ Zx,
    const u16* __restrict__ RT, u16* hbuf, float* h_last, u32* bar) {
  __shared__ u16   h_lds[B_ * D_];         // 64 KB, XOR-swizzled rows
  __shared__ float z_lds[4 * B_ * 128];    // 64 KB: [ks][row][gate*32+u]
  __shared__ u16   zx_lds[B_ * 128];       // 8 KB:  [row][gate*32+u]
  __shared__ float c_lds[B_ * 32];         // 4 KB:  [row][u]
  int tid = threadIdx.x;
  int wg = blockIdx.x;
  int w = tid >> 6, l = tid & 63;
  int cb = w & 1, ks = w >> 1;             // col-half (gates 2cb,2cb+1), k-range ks*256..+256
  c_lds[tid] = 0.f; c_lds[tid + 512] = 0.f;

  // preload B fragments (R^T) into registers: 2 gates x 16 k-steps
  int bcol = l & 31;                         // unit within wg
  int bk = ks * 256 + (l >> 5) * 8;          // k base for this lane
  short8v b0[16], b1[16];
  {
    const u16* R0 = RT + (size_t)((cb * 2 + 0) * 1024 + wg * 32 + bcol) * D_ + bk;
    const u16* R1 = RT + (size_t)((cb * 2 + 1) * 1024 + wg * 32 + bcol) * D_ + bk;
    #pragma unroll
    for (int kt = 0; kt < 16; ++kt) {
      b0[kt] = *(const short8v*)(R0 + kt * 16);
      b1[kt] = *(const short8v*)(R1 + kt * 16);
    }
  }
  // A-fragment addressing (h in LDS, swizzled)
  int arow = l & 31;
  int abyte = arow * 2048;
  int asw = (arow & 7) << 4;
  int akb = (ks * 256 + (l >> 5) * 8) * 2;
  // Zx staging mapping: thread covers [zr][zc..zc+8)
  int zr = tid >> 4;
  int zc = (tid & 15) * 8;
  const u16* ZxT = Zx + (size_t)(zc >> 5) * 1024 + wg * 32 + (zc & 31);
  // gate mapping
  int grow = tid >> 4, gu = (tid & 15) * 2;

  #pragma unroll 1
  for (int t = 0; t < T_; ++t) {
    const u16* hcur = hbuf + (size_t)(t & 1) * (B_ * D_);
    // stage h (64 KB) into swizzled LDS
    #pragma unroll
    for (int j = 0; j < 8; ++j) {
      int byte = j * 8192 + tid * 16;
      short8v v = *(const short8v*)((const char*)hcur + byte);
      int row = byte >> 11;
      *(short8v*)((char*)h_lds + (byte ^ ((row & 7) << 4))) = v;
    }
    // stage Zx[t] slice (8 KB)
    {
      short8v v = *(const short8v*)(ZxT + (size_t)(t * 32 + zr) * N4_);
      *(short8v*)(zx_lds + zr * 128 + zc) = v;
    }
    __syncthreads();

    // K-loop: 16 x (1 ds_read_b128 + 2 mfma 32x32x16)
    f32x16 acc0, acc1;
    #pragma unroll
    for (int i = 0; i < 16; ++i) { acc0[i] = 0.f; acc1[i] = 0.f; }
    #pragma unroll
    for (int kt = 0; kt < 16; ++kt) {
      int byte = abyte + akb + kt * 32;
      short8v a = *(const short8v*)((const char*)h_lds + (byte ^ asw));
      acc0 = __builtin_amdgcn_mfma_f32_32x32x16_bf16(a, b0[kt], acc0, 0, 0, 0);
      acc1 = __builtin_amdgcn_mfma_f32_32x32x16_bf16(a, b1[kt], acc1, 0, 0, 0);
    }
    // write K-partials: D layout row=(reg&3)+8*(reg>>2)+4*(lane>>5), col=lane&31
    #pragma unroll
    for (int r = 0; r < 16; ++r) {
      int rowi = (r & 3) + 8 * (r >> 2) + 4 * (l >> 5);
      z_lds[(ks * B_ + rowi) * 128 + (cb * 2 + 0) * 32 + bcol] = acc0[r];
      z_lds[(ks * B_ + rowi) * 128 + (cb * 2 + 1) * 32 + bcol] = acc1[r];
    }
    __syncthreads();

    // gates: thread -> (grow, gu), (grow, gu+1)
    u16 hb0, hb1; float hf0, hf1;
    {
      int u = gu;
      #define ZS(c) (z_lds[(0*B_+grow)*128+(c)] + z_lds[(1*B_+grow)*128+(c)] \
                   + z_lds[(2*B_+grow)*128+(c)] + z_lds[(3*B_+grow)*128+(c)] \
                   + bf2f(zx_lds[grow*128+(c)]))
      float zi = ZS(u);       float zf = ZS(32 + u);
      float zg = ZS(64 + u);  float zo = ZS(96 + u);
      float c  = c_lds[grow * 32 + u];
      float cn = sigm(zf) * c + sigm(zi) * tanhf(zg);
      float hn = sigm(zo) * tanhf(cn);
      c_lds[grow * 32 + u] = cn; hb0 = f2bf(hn); hf0 = hn;
      u = gu + 1;
      zi = ZS(u); zf = ZS(32 + u); zg = ZS(64 + u); zo = ZS(96 + u);
      c = c_lds[grow * 32 + u];
      cn = sigm(zf) * c + sigm(zi) * tanhf(zg);
      hn = sigm(zo) * tanhf(cn);
      c_lds[grow * 32 + u] = cn; hb1 = f2bf(hn); hf1 = hn;
      #undef ZS
    }
    u16* hnext = hbuf + (size_t)((t + 1) & 1) * (B_ * D_);
    *(u32*)(hnext + grow * D_ + wg * 32 + gu) = (u32)hb0 | ((u32)hb1 << 16);
    if (t == T_ - 1) {
      h_last[grow * D_ + wg * 32 + gu]     = hf0;
      h_last[grow * D_ + wg * 32 + gu + 1] = hf1;
    }
    // device barrier (double-buffered h -> one barrier per step)
    __threadfence();
    __syncthreads();
    if (tid == 0) {
      __hip_atomic_fetch_add(bar, 1u, __ATOMIC_RELEASE, __HIP_MEMORY_SCOPE_AGENT);
      u32 target = (u32)(t + 1) * 32u;
      while (__hip_atomic_load(bar, __ATOMIC_ACQUIRE, __HIP_MEMORY_SCOPE_AGENT) < target) {
        __builtin_amdgcn_s_sleep(2);
      }
    }
    __syncthreads();
    __threadfence();
  }
}

// ---------------- LN2: out = LN(xn + h_last) fp32 ----------------
__global__ __launch_bounds__(256) void ln2_kernel(const u16* __restrict__ xn,
    const float* __restrict__ h_last, const float* __restrict__ gam,
    const float* __restrict__ bet, float* __restrict__ out) {
  int row = blockIdx.x; int tid = threadIdx.x;
  int bi = row >> 9;
  ushort4v xv = *(const ushort4v*)(xn + (size_t)row * D_ + tid * 4);
  float4 hv = *(const float4*)(h_last + (size_t)bi * D_ + tid * 4);
  float s0 = bf2f(xv.x) + hv.x;
  float s1 = bf2f(xv.y) + hv.y;
  float s2 = bf2f(xv.z) + hv.z;
  float s3 = bf2f(xv.w) + hv.w;
  float s = s0 + s1 + s2 + s3;
  float ss = s0*s0 + s1*s1 + s2*s2 + s3*s3;
  #pragma unroll
  for (int o = 32; o > 0; o >>= 1) { s += __shfl_down(s, o); ss += __shfl_down(ss, o); }
  __shared__ float red[8];
  int w = tid >> 6, l = tid & 63;
  if (l == 0) { red[w] = s; red[4 + w] = ss; }
  __syncthreads();
  s  = red[0] + red[1] + red[2] + red[3];
  ss = red[4] + red[5] + red[6] + red[7];
  float mean = s * (1.f / D_);
  float var  = ss * (1.f / D_) - mean * mean;
  float rstd = rsqrtf(var + 1e-3f);
  float4 g = *(const float4*)(gam + tid * 4);
  float4 b = *(const float4*)(bet + tid * 4);
  float4 o4;
  o4.x = (s0 - mean) * rstd * g.x + b.x;
  o4.y = (s1 - mean) * rstd * g.y + b.y;
  o4.z = (s2 - mean) * rstd * g.z + b.z;
  o4.w = (s3 - mean) * rstd * g.w + b.w;
  *(float4*)(out + (size_t)row * D_ + tid * 4) = o4;
}

extern "C" void kernel_launch(void* const* d_in, const int* in_sizes, int n_in,
                              void* d_out, int out_size, void* d_ws, size_t ws_size,
                              hipStream_t stream) {
  const float* x    = (const float*)d_in[0];
  const float* g1   = (const float*)d_in[1];
  const float* b1   = (const float*)d_in[2];
  const float* Wk   = (const float*)d_in[3];
  const float* Wr   = (const float*)d_in[4];
  const float* bias = (const float*)d_in[5];
  const float* g2   = (const float*)d_in[6];
  const float* b2   = (const float*)d_in[7];
  char* ws = (char*)d_ws;
  u16* xn    = (u16*)(ws + OFF_XN);
  u16* Zx    = (u16*)(ws + OFF_ZX);
  u16* KT    = (u16*)(ws + OFF_KT);
  u16* RT    = (u16*)(ws + OFF_RT);
  u16* hbuf  = (u16*)(ws + OFF_HB);
  float* hl  = (float*)(ws + OFF_HL);
  u32* bar   = (u32*)(ws + OFF_BAR);
  float* out = (float*)d_out;

  init_kernel<<<128, 256, 0, stream>>>((u32*)hbuf, bar);
  ln1_kernel<<<B_ * T_, 256, 0, stream>>>(x, g1, b1, xn);
  transpose_bf16<<<dim3(128, 32), dim3(32, 8), 0, stream>>>(Wk, KT);
  transpose_bf16<<<dim3(128, 32), dim3(32, 8), 0, stream>>>(Wr, RT);
  gemm_xk<<<4096, 256, 0, stream>>>(xn, KT, bias, Zx);
  lstm_scan<<<32, 512, 0, stream>>>(Zx, RT, hbuf, hl, bar);
  ln2_kernel<<<B_ * T_, 256, 0, stream>>>(xn, hl, g2, b2, out);
}

// Round 2
// 2719.079 us; speedup vs baseline: 2.8518x; 2.8518x over previous
//
#include <hip/hip_runtime.h>

typedef unsigned short u16;
typedef unsigned int   u32;
typedef unsigned long long u64;
typedef __attribute__((ext_vector_type(8)))  short  short8v;   // 8 x bf16 (as i16)
typedef __attribute__((ext_vector_type(4)))  float  f32x4;
typedef __attribute__((ext_vector_type(16))) float  f32x16;
typedef __attribute__((ext_vector_type(4)))  unsigned short ushort4v;

#define B_   32
#define T_   512
#define D_   1024
#define N4_  4096

// ---- workspace layout (bytes) ----
#define OFF_XN   0ull                 // xn bf16   [32*512*1024]      33554432
#define OFF_ZX   33554432ull          // Zx bf16   [512][32][4096]   134217728
#define OFF_KT   167772160ull         // kernel^T bf16 [4096][1024]    8388608
#define OFF_RT   176160768ull         // recurrent^T bf16 [4096][1024] 8388608
#define OFF_HB   184549376ull         // h double buffer bf16 2*[32][1024]
#define OFF_HL   184680448ull         // h_last fp32 [32][1024]
#define OFF_FLG  184811520ull         // flags: 32 x 64B-strided u32

__device__ inline u16 f2bf(float f) {
  union { float f; u32 u; } x; x.f = f;
  u32 r = x.u + 0x7FFFu + ((x.u >> 16) & 1u);   // RNE
  return (u16)(r >> 16);
}
__device__ inline float bf2f(u16 h) {
  union { u32 u; float f; } x; x.u = ((u32)h) << 16; return x.f;
}
__device__ inline float sigm(float x) { return 1.f / (1.f + __expf(-x)); }

// ---------------- init: zero h buffers + flags ----------------
__global__ __launch_bounds__(256) void init_kernel(u32* hbuf, u32* flags) {
  int i = blockIdx.x * 256 + threadIdx.x;
  if (i < 32768) hbuf[i] = 0u;       // 2 * 32*1024 bf16 = 32768 dwords
  if (i < 32)    flags[i * 16] = 0u; // 64B-strided flags
}

// ---------------- LN1: x fp32 -> xn bf16 ----------------
__global__ __launch_bounds__(256) void ln1_kernel(const float* __restrict__ x,
    const float* __restrict__ gam, const float* __restrict__ bet, u16* __restrict__ xn) {
  int row = blockIdx.x; int tid = threadIdx.x;
  const float* xr = x + (size_t)row * D_;
  float4 v = *(const float4*)(xr + tid * 4);
  float s  = v.x + v.y + v.z + v.w;
  float ss = v.x*v.x + v.y*v.y + v.z*v.z + v.w*v.w;
  #pragma unroll
  for (int o = 32; o > 0; o >>= 1) { s += __shfl_down(s, o); ss += __shfl_down(ss, o); }
  __shared__ float red[8];
  int w = tid >> 6, l = tid & 63;
  if (l == 0) { red[w] = s; red[4 + w] = ss; }
  __syncthreads();
  s  = red[0] + red[1] + red[2] + red[3];
  ss = red[4] + red[5] + red[6] + red[7];
  float mean = s * (1.f / D_);
  float var  = ss * (1.f / D_) - mean * mean;
  float rstd = rsqrtf(var + 1e-3f);
  float4 g = *(const float4*)(gam + tid * 4);
  float4 b = *(const float4*)(bet + tid * 4);
  ushort4v o4;
  o4.x = f2bf((v.x - mean) * rstd * g.x + b.x);
  o4.y = f2bf((v.y - mean) * rstd * g.y + b.y);
  o4.z = f2bf((v.z - mean) * rstd * g.z + b.z);
  o4.w = f2bf((v.w - mean) * rstd * g.w + b.w);
  *(ushort4v*)(xn + (size_t)row * D_ + tid * 4) = o4;
}

// ---------------- transpose [1024][4096] fp32 -> [4096][1024] bf16 ----------------
__global__ __launch_bounds__(256) void transpose_bf16(const float* __restrict__ W, u16* __restrict__ WT) {
  __shared__ float tile[32][33];
  int c0 = blockIdx.x * 32, r0 = blockIdx.y * 32;
  int tx = threadIdx.x, ty = threadIdx.y;
  #pragma unroll
  for (int i = ty; i < 32; i += 8)
    tile[i][tx] = W[(size_t)(r0 + i) * N4_ + c0 + tx];
  __syncthreads();
  #pragma unroll
  for (int i = ty; i < 32; i += 8)
    WT[(size_t)(c0 + i) * D_ + r0 + tx] = f2bf(tile[tx][i]);
}

// ---------------- GEMM: Zx = xn @ kernel + bias ----------------
__global__ __launch_bounds__(256) void gemm_xk(const u16* __restrict__ A, const u16* __restrict__ Bt,
    const float* __restrict__ bias, u16* __restrict__ Zx) {
  __shared__ u16 As[128 * 32];
  __shared__ u16 Bs[128 * 32];
  int tid = threadIdx.x;
  int bm = blockIdx.x >> 5, bn = blockIdx.x & 31;
  int w = tid >> 6, l = tid & 63;
  int srow = tid >> 2, sk = (tid & 3) * 8;        // staging: row j*64+srow, k = sk..sk+8
  const u16* Ag = A  + (size_t)(bm * 128 + srow) * D_ + sk;
  const u16* Bg = Bt + (size_t)(bn * 128 + srow) * D_ + sk;
  int sb0 = (srow * 64 + sk * 2)          ^ ((srow & 3) << 4);
  int sb1 = ((srow + 64) * 64 + sk * 2)   ^ ((srow & 3) << 4);
  int wm = w >> 1, wn = w & 1;
  int frow = l & 15, fko = (l >> 4) * 16;         // fragment k byte offset
  f32x4 acc[4][4];
  #pragma unroll
  for (int mi = 0; mi < 4; ++mi)
    #pragma unroll
    for (int ni = 0; ni < 4; ++ni)
      #pragma unroll
      for (int j = 0; j < 4; ++j) acc[mi][ni][j] = 0.f;

  short8v ap0 = *(const short8v*)(Ag);
  short8v ap1 = *(const short8v*)(Ag + 64 * (size_t)D_);
  short8v bp0 = *(const short8v*)(Bg);
  short8v bp1 = *(const short8v*)(Bg + 64 * (size_t)D_);

  for (int kt = 0; kt < 32; ++kt) {
    __syncthreads();
    *(short8v*)((char*)As + sb0) = ap0;
    *(short8v*)((char*)As + sb1) = ap1;
    *(short8v*)((char*)Bs + sb0) = bp0;
    *(short8v*)((char*)Bs + sb1) = bp1;
    __syncthreads();
    if (kt < 31) {
      ap0 = *(const short8v*)(Ag + (kt + 1) * 32);
      ap1 = *(const short8v*)(Ag + 64 * (size_t)D_ + (kt + 1) * 32);
      bp0 = *(const short8v*)(Bg + (kt + 1) * 32);
      bp1 = *(const short8v*)(Bg + 64 * (size_t)D_ + (kt + 1) * 32);
    }
    short8v af[4], bfr[4];
    #pragma unroll
    for (int mi = 0; mi < 4; ++mi) {
      int r = wm * 64 + mi * 16 + frow;
      af[mi] = *(const short8v*)((char*)As + ((r * 64 + fko) ^ ((r & 3) << 4)));
    }
    #pragma unroll
    for (int ni = 0; ni < 4; ++ni) {
      int r = wn * 64 + ni * 16 + frow;
      bfr[ni] = *(const short8v*)((char*)Bs + ((r * 64 + fko) ^ ((r & 3) << 4)));
    }
    #pragma unroll
    for (int mi = 0; mi < 4; ++mi)
      #pragma unroll
      for (int ni = 0; ni < 4; ++ni)
        acc[mi][ni] = __builtin_amdgcn_mfma_f32_16x16x32_bf16(af[mi], bfr[ni], acc[mi][ni], 0, 0, 0);
  }
  // epilogue: +bias, bf16, remap rows to [t][b]
  #pragma unroll
  for (int mi = 0; mi < 4; ++mi) {
    #pragma unroll
    for (int ni = 0; ni < 4; ++ni) {
      int col = bn * 128 + wn * 64 + ni * 16 + (l & 15);
      float bv = bias[col];
      #pragma unroll
      for (int j = 0; j < 4; ++j) {
        int row = bm * 128 + wm * 64 + mi * 16 + (l >> 4) * 4 + j;
        int zrow = (row & 511) * 32 + (row >> 9);
        Zx[(size_t)zrow * N4_ + col] = f2bf(acc[mi][ni][j] + bv);
      }
    }
  }
}

// ---------------- persistent LSTM scan ----------------
// 32 WGs x 512 thr. WG wg owns units [wg*32, wg*32+32). 8 waves = 2 col-halves x 4 K-splits.
// Cross-WG h exchange: agent-scope relaxed atomics (write-through, bypass non-coherent L2).
// Sync: per-WG monotonic flag (64B-strided); all waves poll; zero cache flushes.
__global__ __launch_bounds__(512, 2) void lstm_scan(const u16* __restrict__ Zx,
    const u16* __restrict__ RT, u16* hbuf, float* h_last, u32* flags) {
  __shared__ u16   h_lds[B_ * D_];         // 64 KB, XOR-swizzled rows
  __shared__ float z_lds[4 * B_ * 128];    // 64 KB: [ks][row][gate*32+u]
  __shared__ u16   zx_lds[B_ * 128];       // 8 KB:  [row][gate*32+u]
  __shared__ float c_lds[B_ * 32];         // 4 KB:  [row][u]
  int tid = threadIdx.x;
  int wg = blockIdx.x;
  int w = tid >> 6, l = tid & 63;
  int cb = w & 1, ks = w >> 1;             // col-half (gates 2cb,2cb+1), k-range ks*256..+256
  c_lds[tid] = 0.f; c_lds[tid + 512] = 0.f;

  // preload B fragments (R^T) into registers: 2 gates x 16 k-steps
  int bcol = l & 31;                         // unit within wg
  int bk = ks * 256 + (l >> 5) * 8;          // k base for this lane
  short8v b0[16], b1[16];
  {
    const u16* R0 = RT + (size_t)((cb * 2 + 0) * 1024 + wg * 32 + bcol) * D_ + bk;
    const u16* R1 = RT + (size_t)((cb * 2 + 1) * 1024 + wg * 32 + bcol) * D_ + bk;
    #pragma unroll
    for (int kt = 0; kt < 16; ++kt) {
      b0[kt] = *(const short8v*)(R0 + kt * 16);
      b1[kt] = *(const short8v*)(R1 + kt * 16);
    }
  }
  // A-fragment addressing (h in LDS, swizzled)
  int arow = l & 31;
  int abyte = arow * 2048;
  int asw = (arow & 7) << 4;
  int akb = (ks * 256 + (l >> 5) * 8) * 2;
  // Zx staging mapping: thread covers [zr][zc..zc+8)
  int zr = tid >> 4;
  int zc = (tid & 15) * 8;
  const u16* ZxT = Zx + (size_t)(zc >> 5) * 1024 + wg * 32 + (zc & 31);
  // gate mapping
  int grow = tid >> 4, gu = (tid & 15) * 2;
  // flag poll pointer: lane L watches WG (tid&31)
  const u32* fp = flags + (size_t)(tid & 31) * 16;

  #pragma unroll 1
  for (int t = 0; t < T_; ++t) {
    // prefetch Zx[t] slice (independent of h readiness -> overlaps the poll)
    short8v zv = *(const short8v*)(ZxT + (size_t)(t * 32 + zr) * N4_);
    // poll: all waves wait until every WG has published h[t]
    while (true) {
      u32 f = __hip_atomic_load(fp, __ATOMIC_RELAXED, __HIP_MEMORY_SCOPE_AGENT);
      if (__all((int)(f >= (u32)t))) break;
      __builtin_amdgcn_s_sleep(1);
    }
    // stage h (64 KB) via coherent 8B loads, batched issue, then swizzled LDS writes
    const u16* hcur = hbuf + (size_t)(t & 1) * (B_ * D_);
    u64 hv0[8], hv1[8];
    #pragma unroll
    for (int j = 0; j < 8; ++j) {
      const u64* p = (const u64*)((const char*)hcur + j * 8192 + tid * 16);
      hv0[j] = __hip_atomic_load(p,     __ATOMIC_RELAXED, __HIP_MEMORY_SCOPE_AGENT);
      hv1[j] = __hip_atomic_load(p + 1, __ATOMIC_RELAXED, __HIP_MEMORY_SCOPE_AGENT);
    }
    *(short8v*)(zx_lds + zr * 128 + zc) = zv;
    #pragma unroll
    for (int j = 0; j < 8; ++j) {
      int byte = j * 8192 + tid * 16;
      int row = byte >> 11;
      char* d = (char*)h_lds + (byte ^ ((row & 7) << 4));
      *(u64*)d       = hv0[j];
      *(u64*)(d + 8) = hv1[j];
    }
    __syncthreads();

    // K-loop: 16 x (1 ds_read_b128 + 2 mfma 32x32x16)
    f32x16 acc0, acc1;
    #pragma unroll
    for (int i = 0; i < 16; ++i) { acc0[i] = 0.f; acc1[i] = 0.f; }
    #pragma unroll
    for (int kt = 0; kt < 16; ++kt) {
      int byte = abyte + akb + kt * 32;
      short8v a = *(const short8v*)((const char*)h_lds + (byte ^ asw));
      acc0 = __builtin_amdgcn_mfma_f32_32x32x16_bf16(a, b0[kt], acc0, 0, 0, 0);
      acc1 = __builtin_amdgcn_mfma_f32_32x32x16_bf16(a, b1[kt], acc1, 0, 0, 0);
    }
    // write K-partials: D layout row=(reg&3)+8*(reg>>2)+4*(lane>>5), col=lane&31
    #pragma unroll
    for (int r = 0; r < 16; ++r) {
      int rowi = (r & 3) + 8 * (r >> 2) + 4 * (l >> 5);
      z_lds[(ks * B_ + rowi) * 128 + (cb * 2 + 0) * 32 + bcol] = acc0[r];
      z_lds[(ks * B_ + rowi) * 128 + (cb * 2 + 1) * 32 + bcol] = acc1[r];
    }
    __syncthreads();

    // gates: thread -> (grow, gu), (grow, gu+1)
    u16 hb0, hb1; float hf0, hf1;
    {
      int u = gu;
      #define ZS(c) (z_lds[(0*B_+grow)*128+(c)] + z_lds[(1*B_+grow)*128+(c)] \
                   + z_lds[(2*B_+grow)*128+(c)] + z_lds[(3*B_+grow)*128+(c)] \
                   + bf2f(zx_lds[grow*128+(c)]))
      float zi = ZS(u);       float zf = ZS(32 + u);
      float zg = ZS(64 + u);  float zo = ZS(96 + u);
      float c  = c_lds[grow * 32 + u];
      float cn = sigm(zf) * c + sigm(zi) * tanhf(zg);
      float hn = sigm(zo) * tanhf(cn);
      c_lds[grow * 32 + u] = cn; hb0 = f2bf(hn); hf0 = hn;
      u = gu + 1;
      zi = ZS(u); zf = ZS(32 + u); zg = ZS(64 + u); zo = ZS(96 + u);
      c = c_lds[grow * 32 + u];
      cn = sigm(zf) * c + sigm(zi) * tanhf(zg);
      hn = sigm(zo) * tanhf(cn);
      c_lds[grow * 32 + u] = cn; hb1 = f2bf(hn); hf1 = hn;
      #undef ZS
    }
    // publish h slice via write-through agent-scope store
    u16* hnext = hbuf + (size_t)((t + 1) & 1) * (B_ * D_);
    u32 hpack = (u32)hb0 | ((u32)hb1 << 16);
    __hip_atomic_store((u32*)(hnext + grow * D_ + wg * 32 + gu), hpack,
                       __ATOMIC_RELAXED, __HIP_MEMORY_SCOPE_AGENT);
    if (t == T_ - 1) {
      h_last[grow * D_ + wg * 32 + gu]     = hf0;
      h_last[grow * D_ + wg * 32 + gu + 1] = hf1;
    }
    // __syncthreads drains vmcnt for every wave's stores, then publish the flag
    __syncthreads();
    if (tid == 0)
      __hip_atomic_store(flags + (size_t)wg * 16, (u32)(t + 1),
                         __ATOMIC_RELAXED, __HIP_MEMORY_SCOPE_AGENT);
  }
}

// ---------------- LN2: out = LN(xn + h_last) fp32 ----------------
__global__ __launch_bounds__(256) void ln2_kernel(const u16* __restrict__ xn,
    const float* __restrict__ h_last, const float* __restrict__ gam,
    const float* __restrict__ bet, float* __restrict__ out) {
  int row = blockIdx.x; int tid = threadIdx.x;
  int bi = row >> 9;
  ushort4v xv = *(const ushort4v*)(xn + (size_t)row * D_ + tid * 4);
  float4 hv = *(const float4*)(h_last + (size_t)bi * D_ + tid * 4);
  float s0 = bf2f(xv.x) + hv.x;
  float s1 = bf2f(xv.y) + hv.y;
  float s2 = bf2f(xv.z) + hv.z;
  float s3 = bf2f(xv.w) + hv.w;
  float s = s0 + s1 + s2 + s3;
  float ss = s0*s0 + s1*s1 + s2*s2 + s3*s3;
  #pragma unroll
  for (int o = 32; o > 0; o >>= 1) { s += __shfl_down(s, o); ss += __shfl_down(ss, o); }
  __shared__ float red[8];
  int w = tid >> 6, l = tid & 63;
  if (l == 0) { red[w] = s; red[4 + w] = ss; }
  __syncthreads();
  s  = red[0] + red[1] + red[2] + red[3];
  ss = red[4] + red[5] + red[6] + red[7];
  float mean = s * (1.f / D_);
  float var  = ss * (1.f / D_) - mean * mean;
  float rstd = rsqrtf(var + 1e-3f);
  float4 g = *(const float4*)(gam + tid * 4);
  float4 b = *(const float4*)(bet + tid * 4);
  float4 o4;
  o4.x = (s0 - mean) * rstd * g.x + b.x;
  o4.y = (s1 - mean) * rstd * g.y + b.y;
  o4.z = (s2 - mean) * rstd * g.z + b.z;
  o4.w = (s3 - mean) * rstd * g.w + b.w;
  *(float4*)(out + (size_t)row * D_ + tid * 4) = o4;
}

extern "C" void kernel_launch(void* const* d_in, const int* in_sizes, int n_in,
                              void* d_out, int out_size, void* d_ws, size_t ws_size,
                              hipStream_t stream) {
  const float* x    = (const float*)d_in[0];
  const float* g1   = (const float*)d_in[1];
  const float* b1   = (const float*)d_in[2];
  const float* Wk   = (const float*)d_in[3];
  const float* Wr   = (const float*)d_in[4];
  const float* bias = (const float*)d_in[5];
  const float* g2   = (const float*)d_in[6];
  const float* b2   = (const float*)d_in[7];
  char* ws = (char*)d_ws;
  u16* xn    = (u16*)(ws + OFF_XN);
  u16* Zx    = (u16*)(ws + OFF_ZX);
  u16* KT    = (u16*)(ws + OFF_KT);
  u16* RT    = (u16*)(ws + OFF_RT);
  u16* hbuf  = (u16*)(ws + OFF_HB);
  float* hl  = (float*)(ws + OFF_HL);
  u32* flg   = (u32*)(ws + OFF_FLG);
  float* out = (float*)d_out;

  init_kernel<<<128, 256, 0, stream>>>((u32*)hbuf, flg);
  ln1_kernel<<<B_ * T_, 256, 0, stream>>>(x, g1, b1, xn);
  transpose_bf16<<<dim3(128, 32), dim3(32, 8), 0, stream>>>(Wk, KT);
  transpose_bf16<<<dim3(128, 32), dim3(32, 8), 0, stream>>>(Wr, RT);
  gemm_xk<<<4096, 256, 0, stream>>>(xn, KT, bias, Zx);
  lstm_scan<<<32, 512, 0, stream>>>(Zx, RT, hbuf, hl, flg);
  ln2_kernel<<<B_ * T_, 256, 0, stream>>>(xn, hl, g2, b2, out);
}